// Round 5
// baseline (704.180 us; speedup 1.0000x reference)
//
#include <hip/hip_runtime.h>
#include <math.h>

#define NEXP 32
#define NTOK 256
#define DIMD 768
#define DHID 2048
#define DBOT 256
#define DOUT 768
#define NSLOT 512

// ---------------- gate: logits -> top2 -> weights; init y with bl; zero z ----------------
__global__ __launch_bounds__(64) void gate_kernel(
    const float* __restrict__ x, const float* __restrict__ gw,
    const float* __restrict__ bl, float* __restrict__ y,
    int* __restrict__ topk_idx, float* __restrict__ topk_w,
    float* __restrict__ z) {
  const int n = blockIdx.x;
  const int l = threadIdx.x;
  {
    float4 zv = {0.f, 0.f, 0.f, 0.f};
    float4* zp = (float4*)(z + n * 512 + l * 8);
    zp[0] = zv; zp[1] = zv;
  }
  const float* xr = x + n * DIMD;
  float xs[12];
#pragma unroll
  for (int j = 0; j < 12; j++) xs[j] = xr[l + 64 * j];
  float logit[NEXP];
#pragma unroll
  for (int e = 0; e < NEXP; e++) {
    const float* g = gw + e * DIMD;
    float p = 0.f;
#pragma unroll
    for (int j = 0; j < 12; j++) p = fmaf(xs[j], g[l + 64 * j], p);
#pragma unroll
    for (int m = 1; m < 64; m <<= 1) p += __shfl_xor(p, m);
    logit[e] = p;
  }
  int i0 = 0; float m0 = logit[0];
#pragma unroll
  for (int e = 1; e < NEXP; e++) { if (logit[e] > m0) { m0 = logit[e]; i0 = e; } }
  int i1 = -1; float m1 = -3.4e38f;
#pragma unroll
  for (int e = 0; e < NEXP; e++) { if (e != i0 && logit[e] > m1) { m1 = logit[e]; i1 = e; } }
  const float e1 = expf(m1 - m0);
  const float w0 = 1.f / (1.f + e1);
  const float w1 = e1 * w0;
  if (l == 0) {
    topk_idx[2 * n] = i0; topk_idx[2 * n + 1] = i1;
    topk_w[2 * n] = w0;  topk_w[2 * n + 1] = w1;
  }
  const float* bl0 = bl + i0 * DOUT;
  const float* bl1 = bl + i1 * DOUT;
#pragma unroll
  for (int j = 0; j < 12; j++) {
    const int o = l + 64 * j;
    y[n * DOUT + o] = fmaf(w0, bl0[o], w1 * bl1[o]);
  }
}

// ---------------- build compact per-expert token lists ----------------
__global__ __launch_bounds__(256) void build_lists(
    const int* __restrict__ topk_idx, const float* __restrict__ topk_w,
    int* __restrict__ counts, int* __restrict__ offsets,
    int* __restrict__ tok_list, float* __restrict__ tok_wt) {
  __shared__ int cnt[NEXP], base[NEXP], fill[NEXP];
  const int t = threadIdx.x;
  if (t < NEXP) { cnt[t] = 0; fill[t] = 0; }
  __syncthreads();
  const int e0 = topk_idx[2 * t], e1 = topk_idx[2 * t + 1];
  atomicAdd(&cnt[e0], 1);
  atomicAdd(&cnt[e1], 1);
  __syncthreads();
  if (t == 0) { int s = 0; for (int i = 0; i < NEXP; i++) { base[i] = s; s += cnt[i]; } }
  __syncthreads();
  const int p0 = atomicAdd(&fill[e0], 1);
  tok_list[base[e0] + p0] = t; tok_wt[base[e0] + p0] = topk_w[2 * t];
  const int p1 = atomicAdd(&fill[e1], 1);
  tok_list[base[e1] + p1] = t; tok_wt[base[e1] + p1] = topk_w[2 * t + 1];
  if (t < NEXP) { counts[t] = cnt[t]; offsets[t] = base[t]; }
}

__device__ __forceinline__ float gelu_f(float v) {
  return 0.5f * v * (1.f + erff(v * 0.70710678118654752f));
}

// compute one K-section: 8 K-slices x (2 cols/lane via float2 weights), 32 tokens,
// distance-1 weight prefetch. Live ~ acc[64] + wa[8] + wb[8] + xv[4] + addr ~= 100
// -> needs the 128-VGPR budget (amdgpu_waves_per_eu(4,4)); at 64 it spills (R2/R3).
template <int SEC>
__device__ __forceinline__ void compute_sec(
    const float* __restrict__ buf, const float* __restrict__ Wseg, int NCT,
    float* acc0, float* acc1, int ks) {
  const int srows = SEC >> 3;          // rows per K-slice
  const int rs = ks * srows;
  const float* wp = Wseg + (size_t)rs * NCT;
  float2 wa[4];
#pragma unroll
  for (int j = 0; j < 4; j++) wa[j] = *(const float2*)(wp + (size_t)j * NCT);
  for (int g = 0; g < srows; g += 4) {
    float2 wb[4];
    const bool more = (g + 4 < srows);
    if (more) {
      const float* wn = wp + (size_t)(g + 4) * NCT;
#pragma unroll
      for (int j = 0; j < 4; j++) wb[j] = *(const float2*)(wn + (size_t)j * NCT);
    }
    const float* bp = buf + rs + g;
#pragma unroll
    for (int t = 0; t < 32; t++) {
      const float4 xv = *(const float4*)(bp + t * SEC);  // wave-uniform LDS broadcast
      acc0[t] = fmaf(xv.x, wa[0].x, acc0[t]);
      acc1[t] = fmaf(xv.x, wa[0].y, acc1[t]);
      acc0[t] = fmaf(xv.y, wa[1].x, acc0[t]);
      acc1[t] = fmaf(xv.y, wa[1].y, acc1[t]);
      acc0[t] = fmaf(xv.z, wa[2].x, acc0[t]);
      acc1[t] = fmaf(xv.z, wa[2].y, acc1[t]);
      acc0[t] = fmaf(xv.w, wa[3].x, acc0[t]);
      acc1[t] = fmaf(xv.w, wa[3].y, acc1[t]);
    }
    if (more) {
#pragma unroll
      for (int j = 0; j < 4; j++) wa[j] = wb[j];
    }
  }
}

// ---------------- generic expert FF layer ----------------
// MODE 0: L1  x(gather tok) @ W1 + b1 -> gelu -> h1
// MODE 1: L2  h1 @ W2 + b2 -> gelu -> h2
// MODE 2: L3  h2 @ W3 (K grid-split, atomicAdd) -> z  (b3 folded into L4)
// MODE 3: L4  (z + b3) @ Wl -> atomicAdd(w_t * val) into y[token]
// Block: 1024 thr = 16 waves = 2 colgroups(128 cols) x 8 K-slices; tile = 256 cols.
// Occupancy is LDS-fixed at 1 block/CU = 4 waves/EU, so pin waves_per_eu(4,4):
// VGPR budget 128, which the ~100-float live set needs (64-budget spilled 267 MB).
template <int MODE>
__global__ __launch_bounds__(1024) __attribute__((amdgpu_waves_per_eu(4, 4)))
void ff_kernel(
    const float* __restrict__ Ain, const float* __restrict__ W,
    const float* __restrict__ Bias, float* __restrict__ Out,
    const int* __restrict__ offsets, const int* __restrict__ counts,
    const int* __restrict__ tok_list, const float* __restrict__ tok_wt,
    int KTOT, int NCT, int INS, int kblocks, int coltiles) {
  __shared__ float lds[32768];  // 128 KiB: 2x64KiB staging dbuf, reused for reduction
  const int tid  = threadIdx.x;
  const int lane = tid & 63;
  const int wave = tid >> 6;
  const int cg   = wave & 1;   // col-group (128 cols each)
  const int ks   = wave >> 1;  // K-slice 0..7
  const int e    = blockIdx.y;
  const int ct   = blockIdx.x % coltiles;
  const int kb   = blockIdx.x / coltiles;
  const int KB   = KTOT / kblocks;
  const int cnt  = counts[e];
  const int off  = offsets[e];
  const int cb   = ct * 256;
  const float* Wblk = W + ((size_t)e * KTOT + (size_t)kb * KB) * NCT + cb;
  const int wcol2 = cg * 128 + 2 * lane;
  const int nsec = (KB + 511) >> 9;

  for (int tc0 = 0; tc0 < cnt; tc0 += 32) {
    const int tcn = min(32, cnt - tc0);
    float acc0[32], acc1[32];
#pragma unroll
    for (int t = 0; t < 32; t++) { acc0[t] = 0.f; acc1[t] = 0.f; }

    // this wave's two staging-source rows
    const float* rowb[2];
#pragma unroll
    for (int i = 0; i < 2; i++) {
      const int slot = off + tc0 + 2 * wave + i;
      const int srow = (MODE == 0) ? tok_list[min(slot, NSLOT - 1)]
                                   : min(slot, NSLOT - 1);
      rowb[i] = Ain + (size_t)srow * INS + (size_t)kb * KB;
    }

    // stage section s into buffer b (global_load_lds for MODE<3; regs+bias for MODE 3)
    auto stage = [&](int b, int s) {
      const int sb  = s << 9;
      const int sec = min(512, KB - sb);
      float* bufp = lds + b * 16384;
      if (MODE == 3) {
        const int t  = tid >> 5;
        const int r0 = (tid & 31) * 8;
        float* dst = bufp + t * sec + r0;
        if (t < tcn) {
          const int slot = off + tc0 + t;
          const float* src = Ain + (size_t)slot * INS + sb + r0;
          const float* bsrc = Bias + e * KTOT + sb + r0;
#pragma unroll
          for (int j = 0; j < 8; j += 4) {
            float4 v = *(const float4*)(src + j);
            const float4 bv = *(const float4*)(bsrc + j);
            v.x += bv.x; v.y += bv.y; v.z += bv.z; v.w += bv.w;
            *(float4*)(dst + j) = v;
          }
        } else {
          const float4 zz = {0.f, 0.f, 0.f, 0.f};
#pragma unroll
          for (int j = 0; j < 8; j += 4) *(float4*)(dst + j) = zz;
        }
      } else {
#pragma unroll
        for (int i = 0; i < 2; i++) {
          const int t = 2 * wave + i;
          float* ldst = bufp + t * sec;
          if (t < tcn) {
            const float* row = rowb[i] + sb;
            for (int c = 0; c < sec; c += 256) {
              __builtin_amdgcn_global_load_lds(
                  (const __attribute__((address_space(1))) void*)(row + c + lane * 4),
                  (__attribute__((address_space(3))) void*)(ldst + c),
                  16, 0, 0);
            }
          } else {
            const float4 zz = {0.f, 0.f, 0.f, 0.f};
            for (int c = 0; c < sec; c += 256)
              *(float4*)(ldst + c + lane * 4) = zz;
          }
        }
      }
    };

    stage(0, 0);
    __syncthreads();
    for (int s = 0; s < nsec; s++) {
      if (s + 1 < nsec) stage((s + 1) & 1, s + 1);
      const int sb  = s << 9;
      const int sec = min(512, KB - sb);
      const float* bufp = lds + (s & 1) * 16384;
      const float* Wseg = Wblk + (size_t)sb * NCT + wcol2;
      if (sec == 512) compute_sec<512>(bufp, Wseg, NCT, acc0, acc1, ks);
      else            compute_sec<256>(bufp, Wseg, NCT, acc0, acc1, ks);
      __syncthreads();
    }

    // ---- reduce 8 K-slices via LDS, emit float2 per thread ----
    const int p  = tid & 127;           // (cg, lane)
    const int t0 = (tid >> 7) << 2;     // 4 tokens per reducer thread
    const int colbase = cb + (p >> 6) * 128 + 2 * (p & 63);
    float sv[4];
#pragma unroll
    for (int t = 0; t < 32; t++) lds[t * 1024 + tid] = acc0[t];
    __syncthreads();
#pragma unroll
    for (int i = 0; i < 4; i++) {
      float s = 0.f;
#pragma unroll
      for (int k2 = 0; k2 < 8; k2++) s += lds[(t0 + i) * 1024 + k2 * 128 + p];
      sv[i] = s;
    }
    __syncthreads();
#pragma unroll
    for (int t = 0; t < 32; t++) lds[t * 1024 + tid] = acc1[t];
    __syncthreads();
#pragma unroll
    for (int i = 0; i < 4; i++) {
      const int t = t0 + i;
      if (t < tcn) {
        float s1 = 0.f;
#pragma unroll
        for (int k2 = 0; k2 < 8; k2++) s1 += lds[t * 1024 + k2 * 128 + p];
        const int slot = off + tc0 + t;
        if (MODE <= 1) {
          const float2 bv = *(const float2*)(Bias + e * NCT + colbase);
          float2 o;
          o.x = gelu_f(sv[i] + bv.x);
          o.y = gelu_f(s1 + bv.y);
          *(float2*)(Out + (size_t)slot * NCT + colbase) = o;
        } else if (MODE == 2) {
          atomicAdd(&Out[(size_t)slot * NCT + colbase], sv[i]);
          atomicAdd(&Out[(size_t)slot * NCT + colbase + 1], s1);
        } else {
          const int trow = tok_list[slot];
          const float wgt = tok_wt[slot];
          atomicAdd(&Out[(size_t)trow * NCT + colbase], wgt * sv[i]);
          atomicAdd(&Out[(size_t)trow * NCT + colbase + 1], wgt * s1);
        }
      }
    }
    __syncthreads();   // protect LDS before next chunk's staging
  }
}

extern "C" void kernel_launch(void* const* d_in, const int* in_sizes, int n_in,
                              void* d_out, int out_size, void* d_ws, size_t ws_size,
                              hipStream_t stream) {
  const float* x  = (const float*)d_in[0];
  const float* gw = (const float*)d_in[1];
  const float* W1 = (const float*)d_in[2];
  const float* b1 = (const float*)d_in[3];
  const float* W2 = (const float*)d_in[4];
  const float* b2 = (const float*)d_in[5];
  const float* W3 = (const float*)d_in[6];
  const float* b3 = (const float*)d_in[7];
  const float* Wl = (const float*)d_in[8];
  const float* bl = (const float*)d_in[9];
  float* y  = (float*)d_out;
  float* ws = (float*)d_ws;

  float* topk_w   = ws;                    // 512 f
  int*   topk_idx = (int*)(ws + 512);      // 512 i
  int*   counts   = (int*)(ws + 1024);     // 32 i
  int*   offsets  = (int*)(ws + 1056);     // 32 i
  int*   tok_list = (int*)(ws + 1088);     // 512 i
  float* tok_wt   = ws + 1600;             // 512 f
  float* h1 = ws + 4096;                   // 512*2048
  float* h2 = h1 + (size_t)NSLOT * DHID;   // 512*2048
  float* z  = h2 + (size_t)NSLOT * DHID;   // 512*256

  gate_kernel<<<NTOK, 64, 0, stream>>>(x, gw, bl, y, topk_idx, topk_w, z);
  build_lists<<<1, 256, 0, stream>>>(topk_idx, topk_w, counts, offsets, tok_list, tok_wt);
  // L1: x[tok,768] @ W1[e,768,2048] -> gelu -> h1       (8 coltiles x 32 experts)
  ff_kernel<0><<<dim3(8, 32), 1024, 0, stream>>>(x,  W1, b1, h1, offsets, counts, tok_list, tok_wt,
                                                 DIMD, DHID, DIMD, 1, 8);
  // L2: h1 @ W2[e,2048,2048] -> gelu -> h2              (8 coltiles x 32 experts)
  ff_kernel<1><<<dim3(8, 32), 1024, 0, stream>>>(h1, W2, b2, h2, offsets, counts, tok_list, tok_wt,
                                                 DHID, DHID, DHID, 1, 8);
  // L3: h2 @ W3[e,2048,256] -> z (atomic over 8 K-blocks)
  ff_kernel<2><<<dim3(8, 32), 1024, 0, stream>>>(h2, W3, nullptr, z, offsets, counts, tok_list, tok_wt,
                                                 DHID, DBOT, DHID, 8, 1);
  // L4: (z+b3) @ Wl[e,256,768] -> y (scatter, weighted) (3 coltiles x 32 experts)
  ff_kernel<3><<<dim3(3, 32), 1024, 0, stream>>>(z,  Wl, b3, y, offsets, counts, tok_list, tok_wt,
                                                 DBOT, DOUT, DBOT, 1, 3);
}

// Round 6
// 543.472 us; speedup vs baseline: 1.2957x; 1.2957x over previous
//
#include <hip/hip_runtime.h>
#include <math.h>

#define NEXP 32
#define NTOK 256
#define DIMD 768
#define DHID 2048
#define DBOT 256
#define DOUT 768
#define NSLOT 512

// ---------------- gate: logits -> top2 -> weights; init y with bl; zero z ----------------
__global__ __launch_bounds__(64) void gate_kernel(
    const float* __restrict__ x, const float* __restrict__ gw,
    const float* __restrict__ bl, float* __restrict__ y,
    int* __restrict__ topk_idx, float* __restrict__ topk_w,
    float* __restrict__ z) {
  const int n = blockIdx.x;
  const int l = threadIdx.x;
  {
    float4 zv = {0.f, 0.f, 0.f, 0.f};
    float4* zp = (float4*)(z + n * 512 + l * 8);
    zp[0] = zv; zp[1] = zv;
  }
  const float* xr = x + n * DIMD;
  float xs[12];
#pragma unroll
  for (int j = 0; j < 12; j++) xs[j] = xr[l + 64 * j];
  float logit[NEXP];
#pragma unroll
  for (int e = 0; e < NEXP; e++) {
    const float* g = gw + e * DIMD;
    float p = 0.f;
#pragma unroll
    for (int j = 0; j < 12; j++) p = fmaf(xs[j], g[l + 64 * j], p);
#pragma unroll
    for (int m = 1; m < 64; m <<= 1) p += __shfl_xor(p, m);
    logit[e] = p;
  }
  int i0 = 0; float m0 = logit[0];
#pragma unroll
  for (int e = 1; e < NEXP; e++) { if (logit[e] > m0) { m0 = logit[e]; i0 = e; } }
  int i1 = -1; float m1 = -3.4e38f;
#pragma unroll
  for (int e = 0; e < NEXP; e++) { if (e != i0 && logit[e] > m1) { m1 = logit[e]; i1 = e; } }
  const float e1 = expf(m1 - m0);
  const float w0 = 1.f / (1.f + e1);
  const float w1 = e1 * w0;
  if (l == 0) {
    topk_idx[2 * n] = i0; topk_idx[2 * n + 1] = i1;
    topk_w[2 * n] = w0;  topk_w[2 * n + 1] = w1;
  }
  const float* bl0 = bl + i0 * DOUT;
  const float* bl1 = bl + i1 * DOUT;
#pragma unroll
  for (int j = 0; j < 12; j++) {
    const int o = l + 64 * j;
    y[n * DOUT + o] = fmaf(w0, bl0[o], w1 * bl1[o]);
  }
}

// ---------------- build compact per-expert token lists ----------------
__global__ __launch_bounds__(256) void build_lists(
    const int* __restrict__ topk_idx, const float* __restrict__ topk_w,
    int* __restrict__ counts, int* __restrict__ offsets,
    int* __restrict__ tok_list, float* __restrict__ tok_wt) {
  __shared__ int cnt[NEXP], base[NEXP], fill[NEXP];
  const int t = threadIdx.x;
  if (t < NEXP) { cnt[t] = 0; fill[t] = 0; }
  __syncthreads();
  const int e0 = topk_idx[2 * t], e1 = topk_idx[2 * t + 1];
  atomicAdd(&cnt[e0], 1);
  atomicAdd(&cnt[e1], 1);
  __syncthreads();
  if (t == 0) { int s = 0; for (int i = 0; i < NEXP; i++) { base[i] = s; s += cnt[i]; } }
  __syncthreads();
  const int p0 = atomicAdd(&fill[e0], 1);
  tok_list[base[e0] + p0] = t; tok_wt[base[e0] + p0] = topk_w[2 * t];
  const int p1 = atomicAdd(&fill[e1], 1);
  tok_list[base[e1] + p1] = t; tok_wt[base[e1] + p1] = topk_w[2 * t + 1];
  if (t < NEXP) { counts[t] = cnt[t]; offsets[t] = base[t]; }
}

__device__ __forceinline__ float gelu_f(float v) {
  return 0.5f * v * (1.f + erff(v * 0.70710678118654752f));
}

// one K-section for one wave: SEC rows x 64 cols (1 col/lane), 32 tokens,
// depth-2 weight prefetch. Live regs ~ acc[32]+wr[8]+xv[4]+addr ~= 55.
template <int SEC>
__device__ __forceinline__ void compute_sec(
    const float* __restrict__ buf, const float* __restrict__ wp, int NCT,
    float* acc) {
  constexpr int ngg = SEC >> 2;     // 4-row groups
  float wr[2][4];
#pragma unroll
  for (int d = 0; d < 2; d++)
#pragma unroll
    for (int j = 0; j < 4; j++) wr[d][j] = wp[(size_t)(4 * d + j) * NCT];
#pragma unroll 2
  for (int gg = 0; gg < ngg; ++gg) {
    const int d = gg & 1;           // static under unroll 2 (ngg is even)
    const float* bp = buf + 4 * gg;
#pragma unroll
    for (int t = 0; t < 32; t++) {
      const float4 xv = *(const float4*)(bp + t * SEC);  // wave-uniform broadcast
      acc[t] = fmaf(xv.x, wr[d][0], acc[t]);
      acc[t] = fmaf(xv.y, wr[d][1], acc[t]);
      acc[t] = fmaf(xv.z, wr[d][2], acc[t]);
      acc[t] = fmaf(xv.w, wr[d][3], acc[t]);
    }
    const int gp = min(gg + 2, ngg - 1);   // clamped prefetch (tail rereads, L2-hot)
#pragma unroll
    for (int j = 0; j < 4; j++) wr[d][j] = wp[(size_t)(4 * gp + j) * NCT];
  }
}

// ---------------- generic expert FF layer ----------------
// 512 thr = 8 waves = 2 K-halves x 4 colgroups(64 cols); tile = 256 cols; chunk = 32 tok.
// Each lane owns 1 col, accumulates its half-K sum in acc[32]; one 2-way LDS add at end.
// MODE 0: L1  x(gather) @ W1 + b1 -> gelu -> h1
// MODE 1: L2  h1 @ W2 + b2 -> gelu -> h2
// MODE 2: L3  h2 @ W3 -> atomicAdd into z (grid K-split, z pre-zeroed by gate)
// MODE 3: L4  (z + b3) @ Wl -> atomicAdd(w_t * val) into y (y pre-init with bl)
template <int MODE>
__global__ __launch_bounds__(512) void ff_kernel(
    const float* __restrict__ Ain, const float* __restrict__ W,
    const float* __restrict__ Bias, float* __restrict__ Out,
    const int* __restrict__ offsets, const int* __restrict__ counts,
    const int* __restrict__ tok_list, const float* __restrict__ tok_wt,
    int KTOT, int NCT, int INS, int kblocks, int coltiles) {
  __shared__ float lds[2][2][32 * 256];  // [half][dbuf][tok-major 32 x sec] = 128 KiB
  const int tid  = threadIdx.x;
  const int lane = tid & 63;
  const int wave = tid >> 6;
  const int cg   = wave & 3;    // colgroup (64 cols)
  const int h    = wave >> 2;   // K-half
  const int e    = blockIdx.y;
  const int ct   = blockIdx.x % coltiles;
  const int kb   = blockIdx.x / coltiles;
  const int KB   = KTOT / kblocks;
  const int HK   = KB >> 1;                 // rows per half
  const int nsec = (HK + 255) >> 8;
  const int cnt  = counts[e];
  const int off  = offsets[e];
  const int cb   = ct * 256;
  const int wcol = cg * 64 + lane;
  const float* Wblk = W + ((size_t)e * KTOT + (size_t)kb * KB) * NCT + cb;

  for (int tc0 = 0; tc0 < cnt; tc0 += 32) {
    const int tcn = min(32, cnt - tc0);
    float acc[32];
#pragma unroll
    for (int t = 0; t < 32; t++) acc[t] = 0.f;

    // stage section s of this wave's half into lds[h][buf]
    auto stage = [&](int buf, int s) {
      if (MODE == 3) {
        // single section (HK=64): all 512 threads stage [32][KB=128] with b3 folded
        const int f   = tid << 3;        // 8 floats/thread, flat token-major
        const int tok = f >> 7;
        const int k0  = f & 127;
        const int slot = min(off + tc0 + tok, NSLOT - 1);
        const float* src  = Ain + (size_t)slot * INS + kb * KB + k0;
        const float* bsrc = Bias + e * KTOT + kb * KB + k0;
#pragma unroll
        for (int i = 0; i < 2; i++) {
          const int k = k0 + i * 4;
          float4 v = *(const float4*)(src + i * 4);
          const float4 bv = *(const float4*)(bsrc + i * 4);
          v.x += bv.x; v.y += bv.y; v.z += bv.z; v.w += bv.w;
          *(float4*)(&lds[k >> 6][buf][tok * 64 + (k & 63)]) = v;
        }
      } else {
        const int sec = min(256, HK - (s << 8));
        const int ls  = 31 - __clz(sec);
        const int ncalls = (sec << 5) >> 8;      // 32*sec/256 one-KiB wave calls
        float* base = &lds[h][buf][0];
        const int basecol = kb * KB + h * HK + (s << 8);
        for (int c = cg; c < ncalls; c += 4) {
          const int f0  = (c << 8) + lane * 4;   // per-lane flat float index
          const int tok = f0 >> ls;
          const int k   = f0 & (sec - 1);
          const int slot = min(off + tc0 + tok, NSLOT - 1);
          const int row  = (MODE == 0) ? tok_list[slot] : slot;
          const float* src = Ain + (size_t)row * INS + basecol + k;
          __builtin_amdgcn_global_load_lds(
              (const __attribute__((address_space(1))) void*)src,
              (__attribute__((address_space(3))) void*)(base + (c << 8)),
              16, 0, 0);
        }
      }
    };

    stage(0, 0);
    __syncthreads();
    int buf = 0;
    for (int s = 0; s < nsec; s++) {
      if (s + 1 < nsec) stage(buf ^ 1, s + 1);
      const int sec = min(256, HK - (s << 8));
      const float* bufp = &lds[h][buf][0];
      const float* wp = Wblk + (size_t)(h * HK + (s << 8)) * NCT + wcol;
      if (sec == 256)      compute_sec<256>(bufp, wp, NCT, acc);
      else if (sec == 128) compute_sec<128>(bufp, wp, NCT, acc);
      else                 compute_sec<64>(bufp, wp, NCT, acc);
      __syncthreads();
      buf ^= 1;
    }

    // ---- 2-way cross-half reduce via LDS, emit ----
    float* red = &lds[0][0][0];   // 32 KiB scratch (post-barrier reuse)
    if (h == 1) {
#pragma unroll
      for (int t = 0; t < 32; t++) red[t * 256 + wcol] = acc[t];
    }
    __syncthreads();
    if (h == 0) {
      const int col = cb + wcol;
      const float bcol = (MODE <= 1) ? Bias[e * NCT + col] : 0.f;
      for (int t = 0; t < tcn; t++) {
        const float s2 = acc[t] + red[t * 256 + wcol];
        const int slot = off + tc0 + t;
        if (MODE <= 1) {
          Out[(size_t)slot * NCT + col] = gelu_f(s2 + bcol);
        } else if (MODE == 2) {
          atomicAdd(&Out[(size_t)slot * NCT + col], s2);
        } else {
          atomicAdd(&Out[(size_t)tok_list[slot] * NCT + col], tok_wt[slot] * s2);
        }
      }
    }
    __syncthreads();   // protect LDS before next chunk's staging
  }
}

extern "C" void kernel_launch(void* const* d_in, const int* in_sizes, int n_in,
                              void* d_out, int out_size, void* d_ws, size_t ws_size,
                              hipStream_t stream) {
  const float* x  = (const float*)d_in[0];
  const float* gw = (const float*)d_in[1];
  const float* W1 = (const float*)d_in[2];
  const float* b1 = (const float*)d_in[3];
  const float* W2 = (const float*)d_in[4];
  const float* b2 = (const float*)d_in[5];
  const float* W3 = (const float*)d_in[6];
  const float* b3 = (const float*)d_in[7];
  const float* Wl = (const float*)d_in[8];
  const float* bl = (const float*)d_in[9];
  float* y  = (float*)d_out;
  float* ws = (float*)d_ws;

  float* topk_w   = ws;                    // 512 f
  int*   topk_idx = (int*)(ws + 512);      // 512 i
  int*   counts   = (int*)(ws + 1024);     // 32 i
  int*   offsets  = (int*)(ws + 1056);     // 32 i
  int*   tok_list = (int*)(ws + 1088);     // 512 i
  float* tok_wt   = ws + 1600;             // 512 f
  float* h1 = ws + 4096;                   // 512*2048
  float* h2 = h1 + (size_t)NSLOT * DHID;   // 512*2048
  float* z  = h2 + (size_t)NSLOT * DHID;   // 512*256

  gate_kernel<<<NTOK, 64, 0, stream>>>(x, gw, bl, y, topk_idx, topk_w, z);
  build_lists<<<1, 256, 0, stream>>>(topk_idx, topk_w, counts, offsets, tok_list, tok_wt);
  // L1: x[tok,768] @ W1 -> gelu -> h1                (8 coltiles x 32 experts, HK=384)
  ff_kernel<0><<<dim3(8, 32), 512, 0, stream>>>(x,  W1, b1, h1, offsets, counts, tok_list, tok_wt,
                                                DIMD, DHID, DIMD, 1, 8);
  // L2: h1 @ W2 -> gelu -> h2                       (8 coltiles x 32 experts, HK=1024)
  ff_kernel<1><<<dim3(8, 32), 512, 0, stream>>>(h1, W2, b2, h2, offsets, counts, tok_list, tok_wt,
                                                DHID, DHID, DHID, 1, 8);
  // L3: h2 @ W3 -> z (8-way grid K-split, atomic)   (8 kblocks x 32 experts, HK=128)
  ff_kernel<2><<<dim3(8, 32), 512, 0, stream>>>(h2, W3, nullptr, z, offsets, counts, tok_list, tok_wt,
                                                DHID, DBOT, DHID, 8, 1);
  // L4: (z+b3) @ Wl -> y (scatter, weighted)        (3 coltiles x 2 kblocks x 32, HK=64)
  ff_kernel<3><<<dim3(6, 32), 512, 0, stream>>>(z,  Wl, b3, y, offsets, counts, tok_list, tok_wt,
                                                DBOT, DOUT, DBOT, 2, 3);
}

// Round 7
// 447.344 us; speedup vs baseline: 1.5741x; 1.2149x over previous
//
#include <hip/hip_runtime.h>
#include <math.h>

#define NEXP 32
#define NTOK 256
#define DIMD 768
#define DHID 2048
#define DBOT 256
#define DOUT 768
#define NSLOT 512

// ---------------- gate: logits -> top2 -> weights; init y with bl; zero z ----------------
__global__ __launch_bounds__(64) void gate_kernel(
    const float* __restrict__ x, const float* __restrict__ gw,
    const float* __restrict__ bl, float* __restrict__ y,
    int* __restrict__ topk_idx, float* __restrict__ topk_w,
    float* __restrict__ z) {
  const int n = blockIdx.x;
  const int l = threadIdx.x;
  {
    float4 zv = {0.f, 0.f, 0.f, 0.f};
    float4* zp = (float4*)(z + n * 512 + l * 8);
    zp[0] = zv; zp[1] = zv;
  }
  const float* xr = x + n * DIMD;
  float xs[12];
#pragma unroll
  for (int j = 0; j < 12; j++) xs[j] = xr[l + 64 * j];
  float logit[NEXP];
#pragma unroll
  for (int e = 0; e < NEXP; e++) {
    const float* g = gw + e * DIMD;
    float p = 0.f;
#pragma unroll
    for (int j = 0; j < 12; j++) p = fmaf(xs[j], g[l + 64 * j], p);
#pragma unroll
    for (int m = 1; m < 64; m <<= 1) p += __shfl_xor(p, m);
    logit[e] = p;
  }
  int i0 = 0; float m0 = logit[0];
#pragma unroll
  for (int e = 1; e < NEXP; e++) { if (logit[e] > m0) { m0 = logit[e]; i0 = e; } }
  int i1 = -1; float m1 = -3.4e38f;
#pragma unroll
  for (int e = 0; e < NEXP; e++) { if (e != i0 && logit[e] > m1) { m1 = logit[e]; i1 = e; } }
  const float e1 = expf(m1 - m0);
  const float w0 = 1.f / (1.f + e1);
  const float w1 = e1 * w0;
  if (l == 0) {
    topk_idx[2 * n] = i0; topk_idx[2 * n + 1] = i1;
    topk_w[2 * n] = w0;  topk_w[2 * n + 1] = w1;
  }
  const float* bl0 = bl + i0 * DOUT;
  const float* bl1 = bl + i1 * DOUT;
#pragma unroll
  for (int j = 0; j < 12; j++) {
    const int o = l + 64 * j;
    y[n * DOUT + o] = fmaf(w0, bl0[o], w1 * bl1[o]);
  }
}

// ---------------- build compact per-expert token lists ----------------
__global__ __launch_bounds__(256) void build_lists(
    const int* __restrict__ topk_idx, const float* __restrict__ topk_w,
    int* __restrict__ counts, int* __restrict__ offsets,
    int* __restrict__ tok_list, float* __restrict__ tok_wt) {
  __shared__ int cnt[NEXP], base[NEXP], fill[NEXP];
  const int t = threadIdx.x;
  if (t < NEXP) { cnt[t] = 0; fill[t] = 0; }
  __syncthreads();
  const int e0 = topk_idx[2 * t], e1 = topk_idx[2 * t + 1];
  atomicAdd(&cnt[e0], 1);
  atomicAdd(&cnt[e1], 1);
  __syncthreads();
  if (t == 0) { int s = 0; for (int i = 0; i < NEXP; i++) { base[i] = s; s += cnt[i]; } }
  __syncthreads();
  const int p0 = atomicAdd(&fill[e0], 1);
  tok_list[base[e0] + p0] = t; tok_wt[base[e0] + p0] = topk_w[2 * t];
  const int p1 = atomicAdd(&fill[e1], 1);
  tok_list[base[e1] + p1] = t; tok_wt[base[e1] + p1] = topk_w[2 * t + 1];
  if (t < NEXP) { counts[t] = cnt[t]; offsets[t] = base[t]; }
}

__device__ __forceinline__ float gelu_f(float v) {
  return 0.5f * v * (1.f + erff(v * 0.70710678118654752f));
}

// one K-section: 4 K-slices x (2 cols/lane via float2 weights), 32 tokens,
// distance-1 weight prefetch. Live ~ acc[64]+wa[8]+wb[8]+xv[4]+addr ~= 95 regs;
// at 512 thr the cap is 256 (launch_bounds(512,2)) -> no spill (R2-R5: 64-cap spilled).
template <int SEC>
__device__ __forceinline__ void compute_sec(
    const float* __restrict__ buf, const float* __restrict__ Wseg, int NCT,
    float* acc0, float* acc1, int ks) {
  const int srows = SEC >> 2;          // rows per K-slice (4 slices)
  const int rs = ks * srows;
  const float* wp = Wseg + (size_t)rs * NCT;
  float2 wa[4];
#pragma unroll
  for (int j = 0; j < 4; j++) wa[j] = *(const float2*)(wp + (size_t)j * NCT);
  for (int g = 0; g < srows; g += 4) {
    float2 wb[4];
    const bool more = (g + 4 < srows);
    if (more) {
      const float* wn = wp + (size_t)(g + 4) * NCT;
#pragma unroll
      for (int j = 0; j < 4; j++) wb[j] = *(const float2*)(wn + (size_t)j * NCT);
    }
    const float* bp = buf + rs + g;
#pragma unroll
    for (int t = 0; t < 32; t++) {
      const float4 xv = *(const float4*)(bp + t * SEC);  // wave-uniform LDS broadcast
      acc0[t] = fmaf(xv.x, wa[0].x, acc0[t]);
      acc1[t] = fmaf(xv.x, wa[0].y, acc1[t]);
      acc0[t] = fmaf(xv.y, wa[1].x, acc0[t]);
      acc1[t] = fmaf(xv.y, wa[1].y, acc1[t]);
      acc0[t] = fmaf(xv.z, wa[2].x, acc0[t]);
      acc1[t] = fmaf(xv.z, wa[2].y, acc1[t]);
      acc0[t] = fmaf(xv.w, wa[3].x, acc0[t]);
      acc1[t] = fmaf(xv.w, wa[3].y, acc1[t]);
    }
    if (more) {
#pragma unroll
      for (int j = 0; j < 4; j++) wa[j] = wb[j];
    }
  }
}

// ---------------- generic expert FF layer ----------------
// MODE 0: L1  x(gather tok) @ W1 + b1 -> gelu -> h1
// MODE 1: L2  h1 @ W2 + b2 -> gelu -> h2
// MODE 2: L3  h2 @ W3 (grid K-split, atomicAdd) -> z  (b3 folded into L4)
// MODE 3: L4  (z + b3) @ Wl -> atomicAdd(w_t * val) into y[token]
// Block: 512 thr = 8 waves = 2 colgroups(128 cols) x 4 K-slices; tile = 256 cols.
// LDS 128 KiB -> 1 block/CU (2 waves/SIMD); VGPR cap 256 -> no spill.
template <int MODE>
__global__ __launch_bounds__(512, 2) void ff_kernel(
    const float* __restrict__ Ain, const float* __restrict__ W,
    const float* __restrict__ Bias, float* __restrict__ Out,
    const int* __restrict__ offsets, const int* __restrict__ counts,
    const int* __restrict__ tok_list, const float* __restrict__ tok_wt,
    int KTOT, int NCT, int INS, int kblocks, int coltiles) {
  __shared__ float lds[32768];  // 128 KiB: 2x64KiB staging dbuf, reused for reduction
  const int tid  = threadIdx.x;
  const int lane = tid & 63;
  const int wave = tid >> 6;
  const int cg   = wave & 1;   // col-group (128 cols each)
  const int ks   = wave >> 1;  // K-slice 0..3
  const int e    = blockIdx.y;
  const int ct   = blockIdx.x % coltiles;
  const int kb   = blockIdx.x / coltiles;
  const int KB   = KTOT / kblocks;
  const int cnt  = counts[e];
  const int off  = offsets[e];
  const int cb   = ct * 256;
  const float* Wblk = W + ((size_t)e * KTOT + (size_t)kb * KB) * NCT + cb;
  const int wcol2 = cg * 128 + 2 * lane;
  const int nsec = (KB + 511) >> 9;

  for (int tc0 = 0; tc0 < cnt; tc0 += 32) {
    const int tcn = min(32, cnt - tc0);
    float acc0[32], acc1[32];
#pragma unroll
    for (int t = 0; t < 32; t++) { acc0[t] = 0.f; acc1[t] = 0.f; }

    // this wave's four staging-source rows
    const float* rowb[4];
#pragma unroll
    for (int i = 0; i < 4; i++) {
      const int slot = off + tc0 + 4 * wave + i;
      const int srow = (MODE == 0) ? tok_list[min(slot, NSLOT - 1)]
                                   : min(slot, NSLOT - 1);
      rowb[i] = Ain + (size_t)srow * INS + (size_t)kb * KB;
    }

    // stage section s into buffer b (global_load_lds for MODE<3; regs+bias for MODE 3)
    auto stage = [&](int b, int s) {
      const int sb  = s << 9;
      const int sec = min(512, KB - sb);
      float* bufp = lds + b * 16384;
      if (MODE == 3) {
        // single section (KB=256): 512 thr stage [32 tok][256] with b3 folded
        const int t  = tid >> 4;             // token 0..31
        const int r0 = (tid & 15) * 16;      // 16 floats per thread
        float* dst = bufp + t * sec + r0;
        if (t < tcn) {
          const int slot = off + tc0 + t;
          const float* src = Ain + (size_t)slot * INS + sb + r0;
          const float* bsrc = Bias + e * KTOT + sb + r0;
#pragma unroll
          for (int j = 0; j < 16; j += 4) {
            float4 v = *(const float4*)(src + j);
            const float4 bv = *(const float4*)(bsrc + j);
            v.x += bv.x; v.y += bv.y; v.z += bv.z; v.w += bv.w;
            *(float4*)(dst + j) = v;
          }
        } else {
          const float4 zz = {0.f, 0.f, 0.f, 0.f};
#pragma unroll
          for (int j = 0; j < 16; j += 4) *(float4*)(dst + j) = zz;
        }
      } else {
#pragma unroll
        for (int i = 0; i < 4; i++) {
          const int t = 4 * wave + i;
          float* ldst = bufp + t * sec;
          if (t < tcn) {
            const float* row = rowb[i] + sb;
            for (int c = 0; c < sec; c += 256) {
              __builtin_amdgcn_global_load_lds(
                  (const __attribute__((address_space(1))) void*)(row + c + lane * 4),
                  (__attribute__((address_space(3))) void*)(ldst + c),
                  16, 0, 0);
            }
          } else {
            const float4 zz = {0.f, 0.f, 0.f, 0.f};
            for (int c = 0; c < sec; c += 256)
              *(float4*)(ldst + c + lane * 4) = zz;
          }
        }
      }
    };

    stage(0, 0);
    __syncthreads();
    for (int s = 0; s < nsec; s++) {
      if (s + 1 < nsec) stage((s + 1) & 1, s + 1);
      const int sb  = s << 9;
      const int sec = min(512, KB - sb);
      const float* bufp = lds + (s & 1) * 16384;
      const float* Wseg = Wblk + (size_t)sb * NCT + wcol2;
      if (sec == 512) compute_sec<512>(bufp, Wseg, NCT, acc0, acc1, ks);
      else            compute_sec<256>(bufp, Wseg, NCT, acc0, acc1, ks);
      __syncthreads();
    }

    // ---- reduce 4 K-slices via LDS, emit float2 per thread ----
    const int p  = tid & 127;           // (cg, lane)
    const int t0 = (tid >> 7) << 3;     // 8 tokens per reducer thread
    const int colbase = cb + (p >> 6) * 128 + 2 * (p & 63);
    float sv[8];
#pragma unroll
    for (int t = 0; t < 32; t++) lds[t * 512 + tid] = acc0[t];
    __syncthreads();
#pragma unroll
    for (int i = 0; i < 8; i++) {
      float s = 0.f;
#pragma unroll
      for (int k2 = 0; k2 < 4; k2++) s += lds[(t0 + i) * 512 + k2 * 128 + p];
      sv[i] = s;
    }
    __syncthreads();
#pragma unroll
    for (int t = 0; t < 32; t++) lds[t * 512 + tid] = acc1[t];
    __syncthreads();
#pragma unroll
    for (int i = 0; i < 8; i++) {
      const int t = t0 + i;
      if (t < tcn) {
        float s1 = 0.f;
#pragma unroll
        for (int k2 = 0; k2 < 4; k2++) s1 += lds[t * 512 + k2 * 128 + p];
        const int slot = off + tc0 + t;
        if (MODE <= 1) {
          const float2 bv = *(const float2*)(Bias + e * NCT + colbase);
          float2 o;
          o.x = gelu_f(sv[i] + bv.x);
          o.y = gelu_f(s1 + bv.y);
          *(float2*)(Out + (size_t)slot * NCT + colbase) = o;
        } else if (MODE == 2) {
          atomicAdd(&Out[(size_t)slot * NCT + colbase], sv[i]);
          atomicAdd(&Out[(size_t)slot * NCT + colbase + 1], s1);
        } else {
          const int trow = tok_list[slot];
          const float wgt = tok_wt[slot];
          atomicAdd(&Out[(size_t)trow * NCT + colbase], wgt * sv[i]);
          atomicAdd(&Out[(size_t)trow * NCT + colbase + 1], wgt * s1);
        }
      }
    }
    __syncthreads();   // protect LDS before next chunk's staging
  }
}

extern "C" void kernel_launch(void* const* d_in, const int* in_sizes, int n_in,
                              void* d_out, int out_size, void* d_ws, size_t ws_size,
                              hipStream_t stream) {
  const float* x  = (const float*)d_in[0];
  const float* gw = (const float*)d_in[1];
  const float* W1 = (const float*)d_in[2];
  const float* b1 = (const float*)d_in[3];
  const float* W2 = (const float*)d_in[4];
  const float* b2 = (const float*)d_in[5];
  const float* W3 = (const float*)d_in[6];
  const float* b3 = (const float*)d_in[7];
  const float* Wl = (const float*)d_in[8];
  const float* bl = (const float*)d_in[9];
  float* y  = (float*)d_out;
  float* ws = (float*)d_ws;

  float* topk_w   = ws;                    // 512 f
  int*   topk_idx = (int*)(ws + 512);      // 512 i
  int*   counts   = (int*)(ws + 1024);     // 32 i
  int*   offsets  = (int*)(ws + 1056);     // 32 i
  int*   tok_list = (int*)(ws + 1088);     // 512 i
  float* tok_wt   = ws + 1600;             // 512 f
  float* h1 = ws + 4096;                   // 512*2048
  float* h2 = h1 + (size_t)NSLOT * DHID;   // 512*2048
  float* z  = h2 + (size_t)NSLOT * DHID;   // 512*256

  gate_kernel<<<NTOK, 64, 0, stream>>>(x, gw, bl, y, topk_idx, topk_w, z);
  build_lists<<<1, 256, 0, stream>>>(topk_idx, topk_w, counts, offsets, tok_list, tok_wt);
  // L1: x[tok,768] @ W1[e,768,2048] -> gelu -> h1       (8 coltiles x 32 experts)
  ff_kernel<0><<<dim3(8, 32), 512, 0, stream>>>(x,  W1, b1, h1, offsets, counts, tok_list, tok_wt,
                                                DIMD, DHID, DIMD, 1, 8);
  // L2: h1 @ W2[e,2048,2048] -> gelu -> h2              (8 coltiles x 32 experts)
  ff_kernel<1><<<dim3(8, 32), 512, 0, stream>>>(h1, W2, b2, h2, offsets, counts, tok_list, tok_wt,
                                                DHID, DHID, DHID, 1, 8);
  // L3: h2 @ W3[e,2048,256] -> z (atomic over 8 K-blocks)
  ff_kernel<2><<<dim3(8, 32), 512, 0, stream>>>(h2, W3, nullptr, z, offsets, counts, tok_list, tok_wt,
                                                DHID, DBOT, DHID, 8, 1);
  // L4: (z+b3) @ Wl[e,256,768] -> y (scatter, weighted) (3 coltiles x 32 experts)
  ff_kernel<3><<<dim3(3, 32), 512, 0, stream>>>(z,  Wl, b3, y, offsets, counts, tok_list, tok_wt,
                                                DBOT, DOUT, DBOT, 1, 3);
}

// Round 8
// 400.187 us; speedup vs baseline: 1.7596x; 1.1178x over previous
//
#include <hip/hip_runtime.h>
#include <math.h>

#define NEXP 32
#define NTOK 256
#define DIMD 768
#define DHID 2048
#define DBOT 256
#define DOUT 768
#define NSLOT 512

// ---------------- gate: logits -> top2 -> weights; init y with bl; zero z ----------------
__global__ __launch_bounds__(64) void gate_kernel(
    const float* __restrict__ x, const float* __restrict__ gw,
    const float* __restrict__ bl, float* __restrict__ y,
    int* __restrict__ topk_idx, float* __restrict__ topk_w,
    float* __restrict__ z) {
  const int n = blockIdx.x;
  const int l = threadIdx.x;
  {
    float4 zv = {0.f, 0.f, 0.f, 0.f};
    float4* zp = (float4*)(z + n * 512 + l * 8);
    zp[0] = zv; zp[1] = zv;
  }
  const float* xr = x + n * DIMD;
  float xs[12];
#pragma unroll
  for (int j = 0; j < 12; j++) xs[j] = xr[l + 64 * j];
  float logit[NEXP];
#pragma unroll
  for (int e = 0; e < NEXP; e++) {
    const float* g = gw + e * DIMD;
    float p = 0.f;
#pragma unroll
    for (int j = 0; j < 12; j++) p = fmaf(xs[j], g[l + 64 * j], p);
#pragma unroll
    for (int m = 1; m < 64; m <<= 1) p += __shfl_xor(p, m);
    logit[e] = p;
  }
  int i0 = 0; float m0 = logit[0];
#pragma unroll
  for (int e = 1; e < NEXP; e++) { if (logit[e] > m0) { m0 = logit[e]; i0 = e; } }
  int i1 = -1; float m1 = -3.4e38f;
#pragma unroll
  for (int e = 0; e < NEXP; e++) { if (e != i0 && logit[e] > m1) { m1 = logit[e]; i1 = e; } }
  const float e1 = expf(m1 - m0);
  const float w0 = 1.f / (1.f + e1);
  const float w1 = e1 * w0;
  if (l == 0) {
    topk_idx[2 * n] = i0; topk_idx[2 * n + 1] = i1;
    topk_w[2 * n] = w0;  topk_w[2 * n + 1] = w1;
  }
  const float* bl0 = bl + i0 * DOUT;
  const float* bl1 = bl + i1 * DOUT;
#pragma unroll
  for (int j = 0; j < 12; j++) {
    const int o = l + 64 * j;
    y[n * DOUT + o] = fmaf(w0, bl0[o], w1 * bl1[o]);
  }
}

// ---------------- build compact per-expert token lists ----------------
__global__ __launch_bounds__(256) void build_lists(
    const int* __restrict__ topk_idx, const float* __restrict__ topk_w,
    int* __restrict__ counts, int* __restrict__ offsets,
    int* __restrict__ tok_list, float* __restrict__ tok_wt) {
  __shared__ int cnt[NEXP], base[NEXP], fill[NEXP];
  const int t = threadIdx.x;
  if (t < NEXP) { cnt[t] = 0; fill[t] = 0; }
  __syncthreads();
  const int e0 = topk_idx[2 * t], e1 = topk_idx[2 * t + 1];
  atomicAdd(&cnt[e0], 1);
  atomicAdd(&cnt[e1], 1);
  __syncthreads();
  if (t == 0) { int s = 0; for (int i = 0; i < NEXP; i++) { base[i] = s; s += cnt[i]; } }
  __syncthreads();
  const int p0 = atomicAdd(&fill[e0], 1);
  tok_list[base[e0] + p0] = t; tok_wt[base[e0] + p0] = topk_w[2 * t];
  const int p1 = atomicAdd(&fill[e1], 1);
  tok_list[base[e1] + p1] = t; tok_wt[base[e1] + p1] = topk_w[2 * t + 1];
  if (t < NEXP) { counts[t] = cnt[t]; offsets[t] = base[t]; }
}

__device__ __forceinline__ float gelu_f(float v) {
  return 0.5f * v * (1.f + erff(v * 0.70710678118654752f));
}

// one K-section: 4 K-slices x (2 cols/lane via float2 weights), 32 tokens.
// DEPTH-3 weight prefetch: 4-slot rotating buffer, loads issued 2 groups (1024 cy)
// ahead of use -> covers ~900 cy HBM latency; ~4 KB outstanding per wave.
// ngg (= SEC/16) is a multiple of 4 for every SEC used (512, 256), so
// #pragma unroll 4 makes cur/nxt indices compile-time (rule: no dynamic
// ext-vector indexing -> no scratch).
template <int SEC>
__device__ __forceinline__ void compute_sec(
    const float* __restrict__ buf, const float* __restrict__ Wseg, int NCT,
    float* acc0, float* acc1, int ks) {
  const int srows = SEC >> 2;          // rows per K-slice (4 slices)
  const int rs = ks * srows;
  const float* wp = Wseg + (size_t)rs * NCT;
  constexpr int ngg = SEC >> 4;        // 4-row groups in this slice
  float2 wbuf[4][4];
#pragma unroll
  for (int j = 0; j < 4; j++) {
    wbuf[0][j] = *(const float2*)(wp + (size_t)j * NCT);
    wbuf[1][j] = *(const float2*)(wp + (size_t)(4 + j) * NCT);
  }
#pragma unroll 4
  for (int g = 0; g < ngg; ++g) {
    const int cur = g & 3;
    const int nxt = (g + 2) & 3;
    const int gp  = min(g + 2, ngg - 1);   // clamped tail prefetch (L2-hot reread)
    const float* wn = wp + (size_t)(4 * gp) * NCT;
#pragma unroll
    for (int j = 0; j < 4; j++) wbuf[nxt][j] = *(const float2*)(wn + (size_t)j * NCT);
    const float* bp = buf + rs + 4 * g;
#pragma unroll
    for (int t = 0; t < 32; t++) {
      const float4 xv = *(const float4*)(bp + t * SEC);  // wave-uniform LDS broadcast
      acc0[t] = fmaf(xv.x, wbuf[cur][0].x, acc0[t]);
      acc1[t] = fmaf(xv.x, wbuf[cur][0].y, acc1[t]);
      acc0[t] = fmaf(xv.y, wbuf[cur][1].x, acc0[t]);
      acc1[t] = fmaf(xv.y, wbuf[cur][1].y, acc1[t]);
      acc0[t] = fmaf(xv.z, wbuf[cur][2].x, acc0[t]);
      acc1[t] = fmaf(xv.z, wbuf[cur][2].y, acc1[t]);
      acc0[t] = fmaf(xv.w, wbuf[cur][3].x, acc0[t]);
      acc1[t] = fmaf(xv.w, wbuf[cur][3].y, acc1[t]);
    }
  }
}

// ---------------- generic expert FF layer ----------------
// MODE 0: L1  x(gather tok) @ W1 + b1 -> gelu -> h1
// MODE 1: L2  h1 @ W2 + b2 -> gelu -> h2
// MODE 2: L3  h2 @ W3 (grid K-split, atomicAdd) -> z  (b3 folded into L4)
// MODE 3: L4  (z + b3) @ Wl -> atomicAdd(w_t * val) into y[token]
// Block: 512 thr = 8 waves = 2 colgroups(128 cols) x 4 K-slices; tile = 256 cols.
// LDS 128 KiB -> 1 block/CU (2 waves/SIMD); VGPR cap 256 -> no spill.
template <int MODE>
__global__ __launch_bounds__(512, 2) void ff_kernel(
    const float* __restrict__ Ain, const float* __restrict__ W,
    const float* __restrict__ Bias, float* __restrict__ Out,
    const int* __restrict__ offsets, const int* __restrict__ counts,
    const int* __restrict__ tok_list, const float* __restrict__ tok_wt,
    int KTOT, int NCT, int INS, int kblocks, int coltiles) {
  __shared__ float lds[32768];  // 128 KiB: 2x64KiB staging dbuf, reused for reduction
  const int tid  = threadIdx.x;
  const int lane = tid & 63;
  const int wave = tid >> 6;
  const int cg   = wave & 1;   // col-group (128 cols each)
  const int ks   = wave >> 1;  // K-slice 0..3
  const int e    = blockIdx.y;
  const int ct   = blockIdx.x % coltiles;
  const int kb   = blockIdx.x / coltiles;
  const int KB   = KTOT / kblocks;
  const int cnt  = counts[e];
  const int off  = offsets[e];
  const int cb   = ct * 256;
  const float* Wblk = W + ((size_t)e * KTOT + (size_t)kb * KB) * NCT + cb;
  const int wcol2 = cg * 128 + 2 * lane;
  const int nsec = (KB + 511) >> 9;

  for (int tc0 = 0; tc0 < cnt; tc0 += 32) {
    const int tcn = min(32, cnt - tc0);
    float acc0[32], acc1[32];
#pragma unroll
    for (int t = 0; t < 32; t++) { acc0[t] = 0.f; acc1[t] = 0.f; }

    // this wave's four staging-source rows
    const float* rowb[4];
#pragma unroll
    for (int i = 0; i < 4; i++) {
      const int slot = off + tc0 + 4 * wave + i;
      const int srow = (MODE == 0) ? tok_list[min(slot, NSLOT - 1)]
                                   : min(slot, NSLOT - 1);
      rowb[i] = Ain + (size_t)srow * INS + (size_t)kb * KB;
    }

    // stage section s into buffer b (global_load_lds for MODE<3; regs+bias for MODE 3)
    auto stage = [&](int b, int s) {
      const int sb  = s << 9;
      const int sec = min(512, KB - sb);
      float* bufp = lds + b * 16384;
      if (MODE == 3) {
        // single section (KB=256): 512 thr stage [32 tok][256] with b3 folded
        const int t  = tid >> 4;             // token 0..31
        const int r0 = (tid & 15) * 16;      // 16 floats per thread
        float* dst = bufp + t * sec + r0;
        if (t < tcn) {
          const int slot = off + tc0 + t;
          const float* src = Ain + (size_t)slot * INS + sb + r0;
          const float* bsrc = Bias + e * KTOT + sb + r0;
#pragma unroll
          for (int j = 0; j < 16; j += 4) {
            float4 v = *(const float4*)(src + j);
            const float4 bv = *(const float4*)(bsrc + j);
            v.x += bv.x; v.y += bv.y; v.z += bv.z; v.w += bv.w;
            *(float4*)(dst + j) = v;
          }
        } else {
          const float4 zz = {0.f, 0.f, 0.f, 0.f};
#pragma unroll
          for (int j = 0; j < 16; j += 4) *(float4*)(dst + j) = zz;
        }
      } else {
#pragma unroll
        for (int i = 0; i < 4; i++) {
          const int t = 4 * wave + i;
          float* ldst = bufp + t * sec;
          if (t < tcn) {
            const float* row = rowb[i] + sb;
            for (int c = 0; c < sec; c += 256) {
              __builtin_amdgcn_global_load_lds(
                  (const __attribute__((address_space(1))) void*)(row + c + lane * 4),
                  (__attribute__((address_space(3))) void*)(ldst + c),
                  16, 0, 0);
            }
          } else {
            const float4 zz = {0.f, 0.f, 0.f, 0.f};
            for (int c = 0; c < sec; c += 256)
              *(float4*)(ldst + c + lane * 4) = zz;
          }
        }
      }
    };

    stage(0, 0);
    __syncthreads();
    for (int s = 0; s < nsec; s++) {
      if (s + 1 < nsec) stage((s + 1) & 1, s + 1);
      const int sb  = s << 9;
      const int sec = min(512, KB - sb);
      const float* bufp = lds + (s & 1) * 16384;
      const float* Wseg = Wblk + (size_t)sb * NCT + wcol2;
      if (sec == 512) compute_sec<512>(bufp, Wseg, NCT, acc0, acc1, ks);
      else            compute_sec<256>(bufp, Wseg, NCT, acc0, acc1, ks);
      __syncthreads();
    }

    // ---- reduce 4 K-slices via LDS, emit float2 per thread ----
    const int p  = tid & 127;           // (cg, lane)
    const int t0 = (tid >> 7) << 3;     // 8 tokens per reducer thread
    const int colbase = cb + (p >> 6) * 128 + 2 * (p & 63);
    float sv[8];
#pragma unroll
    for (int t = 0; t < 32; t++) lds[t * 512 + tid] = acc0[t];
    __syncthreads();
#pragma unroll
    for (int i = 0; i < 8; i++) {
      float s = 0.f;
#pragma unroll
      for (int k2 = 0; k2 < 4; k2++) s += lds[(t0 + i) * 512 + k2 * 128 + p];
      sv[i] = s;
    }
    __syncthreads();
#pragma unroll
    for (int t = 0; t < 32; t++) lds[t * 512 + tid] = acc1[t];
    __syncthreads();
#pragma unroll
    for (int i = 0; i < 8; i++) {
      const int t = t0 + i;
      if (t < tcn) {
        float s1 = 0.f;
#pragma unroll
        for (int k2 = 0; k2 < 4; k2++) s1 += lds[t * 512 + k2 * 128 + p];
        const int slot = off + tc0 + t;
        if (MODE <= 1) {
          const float2 bv = *(const float2*)(Bias + e * NCT + colbase);
          float2 o;
          o.x = gelu_f(sv[i] + bv.x);
          o.y = gelu_f(s1 + bv.y);
          *(float2*)(Out + (size_t)slot * NCT + colbase) = o;
        } else if (MODE == 2) {
          atomicAdd(&Out[(size_t)slot * NCT + colbase], sv[i]);
          atomicAdd(&Out[(size_t)slot * NCT + colbase + 1], s1);
        } else {
          const int trow = tok_list[slot];
          const float wgt = tok_wt[slot];
          atomicAdd(&Out[(size_t)trow * NCT + colbase], wgt * sv[i]);
          atomicAdd(&Out[(size_t)trow * NCT + colbase + 1], wgt * s1);
        }
      }
    }
    __syncthreads();   // protect LDS before next chunk's staging
  }
}

extern "C" void kernel_launch(void* const* d_in, const int* in_sizes, int n_in,
                              void* d_out, int out_size, void* d_ws, size_t ws_size,
                              hipStream_t stream) {
  const float* x  = (const float*)d_in[0];
  const float* gw = (const float*)d_in[1];
  const float* W1 = (const float*)d_in[2];
  const float* b1 = (const float*)d_in[3];
  const float* W2 = (const float*)d_in[4];
  const float* b2 = (const float*)d_in[5];
  const float* W3 = (const float*)d_in[6];
  const float* b3 = (const float*)d_in[7];
  const float* Wl = (const float*)d_in[8];
  const float* bl = (const float*)d_in[9];
  float* y  = (float*)d_out;
  float* ws = (float*)d_ws;

  float* topk_w   = ws;                    // 512 f
  int*   topk_idx = (int*)(ws + 512);      // 512 i
  int*   counts   = (int*)(ws + 1024);     // 32 i
  int*   offsets  = (int*)(ws + 1056);     // 32 i
  int*   tok_list = (int*)(ws + 1088);     // 512 i
  float* tok_wt   = ws + 1600;             // 512 f
  float* h1 = ws + 4096;                   // 512*2048
  float* h2 = h1 + (size_t)NSLOT * DHID;   // 512*2048
  float* z  = h2 + (size_t)NSLOT * DHID;   // 512*256

  gate_kernel<<<NTOK, 64, 0, stream>>>(x, gw, bl, y, topk_idx, topk_w, z);
  build_lists<<<1, 256, 0, stream>>>(topk_idx, topk_w, counts, offsets, tok_list, tok_wt);
  // L1: x[tok,768] @ W1[e,768,2048] -> gelu -> h1       (8 coltiles x 32 experts)
  ff_kernel<0><<<dim3(8, 32), 512, 0, stream>>>(x,  W1, b1, h1, offsets, counts, tok_list, tok_wt,
                                                DIMD, DHID, DIMD, 1, 8);
  // L2: h1 @ W2[e,2048,2048] -> gelu -> h2              (8 coltiles x 32 experts)
  ff_kernel<1><<<dim3(8, 32), 512, 0, stream>>>(h1, W2, b2, h2, offsets, counts, tok_list, tok_wt,
                                                DHID, DHID, DHID, 1, 8);
  // L3: h2 @ W3[e,2048,256] -> z (atomic over 8 K-blocks)
  ff_kernel<2><<<dim3(8, 32), 512, 0, stream>>>(h2, W3, nullptr, z, offsets, counts, tok_list, tok_wt,
                                                DHID, DBOT, DHID, 8, 1);
  // L4: (z+b3) @ Wl[e,256,768] -> y (scatter, weighted) (3 coltiles x 32 experts)
  ff_kernel<3><<<dim3(3, 32), 512, 0, stream>>>(z,  Wl, b3, y, offsets, counts, tok_list, tok_wt,
                                                DBOT, DOUT, DBOT, 1, 3);
}